// Round 14
// baseline (278.538 us; speedup 1.0000x reference)
//
#include <hip/hip_runtime.h>
#include <math.h>

// Problem constants (fixed by reference: enc (32,64,64,64) fp32, embed (512,64) fp32)
#define DQ 64
#define KQ 512
#define NVEC 131072
#define QOUT_SIZE (NVEC * DQ)              // 8388608
#define LOSS_OFF QOUT_SIZE
#define IDX_OFF (QOUT_SIZE + 1)

#define RPW 32                             // rows per wave (2 MFMA A-tiles)
#define WPB 4                              // waves per block (256 threads)
#define VPB (RPW * WPB)                    // 128 rows per block
#define NBLK (NVEC / VPB)                  // 1024 blocks -> 4 per CU
#define SC 64                              // codes per LDS stage
#define NST (KQ / SC)                      // 8 stages
#define SDQ (SC * DQ)                      // 4096 shorts per (hi) stage
#define PADS 2654                          // pad shorts: total LDS ~30.1 KB -> exactly 5 WGs/CU
#define SDQ_P (SDQ + PADS)
#define TIE_THR 0.2f                       // fp64 rescan when top-2 gap below this
// Error budget for thr 0.2: surrogate d2' = e_sq - 2*x*e_hi (exact x, bf16 e).
// gap error = 2*x*(el_c1 - el_c2): sigma ~0.026 -> max over 131k rows ~0.15;
// + mantissa-packing perturbation <=0.016. 0.2 = ~7.7 sigma -> flip prob ~0.

typedef __attribute__((ext_vector_type(8))) short short8;          // 8 bf16 = 1 MFMA A/B frag
typedef __attribute__((ext_vector_type(4))) float f32x4;           // MFMA C/D frag

static __device__ __forceinline__ unsigned short f2bf(float f) {   // RNE fp32->bf16
    unsigned u = __float_as_uint(f);
    u += 0x7fff + ((u >> 16) & 1);
    return (unsigned short)(u >> 16);
}
static __device__ __forceinline__ float bf2f(unsigned short h) {
    return __uint_as_float(((unsigned)h) << 16);
}
static __device__ __forceinline__ void cvt8(float4 a, float4 b, short8& hi, short8& lo) {
#define C1(I, V) { unsigned short _h = f2bf(V); hi[I] = (short)_h; lo[I] = (short)f2bf((V) - bf2f(_h)); }
    C1(0, a.x) C1(1, a.y) C1(2, a.z) C1(3, a.w)
    C1(4, b.x) C1(5, b.y) C1(6, b.z) C1(7, b.w)
#undef C1
}

// Init: bf16-HI codebook only (B-lo dropped from the k-loop this round), in
// XOR-SWIZZLED layout (chunk c of row k at slot c ^ (k&7)) for conflict-light
// ds_read_b128 B-frag reads. Plus exact e_sq and loss zeroing.
__global__ void vq_init_kernel(const float* __restrict__ embed,
                               unsigned short* __restrict__ ehi,
                               float* __restrict__ esq,
                               float* __restrict__ out) {
    const int t = blockIdx.x * 64 + threadIdx.x;   // 0..4095
    if (t == 0) out[LOSS_OFF] = 0.0f;
    const int k = t >> 3;            // codebook row
    const int c = t & 7;             // 16-byte chunk (8 dims)
    const float4* p = (const float4*)(embed + (size_t)k * DQ + c * 8);
    float4 a = p[0], b = p[1];
    unsigned short h0 = f2bf(a.x), h1 = f2bf(a.y), h2 = f2bf(a.z), h3 = f2bf(a.w);
    unsigned short h4 = f2bf(b.x), h5 = f2bf(b.y), h6 = f2bf(b.z), h7 = f2bf(b.w);
    short8 hi = { (short)h0, (short)h1, (short)h2, (short)h3,
                  (short)h4, (short)h5, (short)h6, (short)h7 };
    const int slot = c ^ (k & 7);    // XOR swizzle
    *(short8*)(ehi + (size_t)k * DQ + slot * 8) = hi;

    float ps = 0.f;
    ps = fmaf(a.x, a.x, ps); ps = fmaf(a.y, a.y, ps); ps = fmaf(a.z, a.z, ps); ps = fmaf(a.w, a.w, ps);
    ps = fmaf(b.x, b.x, ps); ps = fmaf(b.y, b.y, ps); ps = fmaf(b.z, b.z, ps); ps = fmaf(b.w, b.w, ps);
    ps += __shfl_xor(ps, 1);
    ps += __shfl_xor(ps, 2);
    ps += __shfl_xor(ps, 4);
    if (c == 0) esq[k] = ps;
}

// R12/R13 CONFIRMED allocator rule: VGPR budget = 512 / (provable max
// waves/SIMD from LDS+slots); attributes ignored. R13: 4 waves/SIMD, 124
// regs, no spill, 74 us, pipes <30% -> still latency-bound. This round:
// 5 waves/SIMD (LDS padded to ~30.1 KB -> exactly 5 WGs/CU -> budget ~102)
// with demand cut to ~90 by (a) dropping B-lo: dot(x, e_hi) with exactly
// split x = 4 MFMAs/acc, half the B regs/staging/LDS traffic; surrogate
// error covered by TIE_THR=0.2 + full fp64 rescan of flagged rows;
// (b) packing the 9-bit code into the d2 mantissa (kills i1[8]).
// R6-R9: no global loads in the k-loop. R3: unrolled-constant reg indexing.
__global__ __launch_bounds__(256) void vq_mfma_kernel(const float* __restrict__ enc,
                                                      const float* __restrict__ embed,
                                                      const unsigned short* __restrict__ ehi,
                                                      const float* __restrict__ esq,
                                                      float* __restrict__ out) {
    __shared__ unsigned short hs[2 * SDQ_P];   // hi stages (dbuf, padded): 27.0 KB
    __shared__ float esq_s[KQ];                // 2 KB
    __shared__ int bidx_s[VPB];                // 0.5 KB
    __shared__ int flag_s[VPB];                // 0.5 KB
    __shared__ float red[WPB];

    const int tid = threadIdx.x;
    const int lane = tid & 63;
    const int w = tid >> 6;            // wave 0..3
    const int l15 = lane & 15;
    const int l4 = lane >> 4;          // 0..3
    const int vb = blockIdx.x * VPB + w * RPW;

    esq_s[tid] = esq[tid];
    esq_s[tid + 256] = esq[tid + 256];

    // A fragments for 2 tiles: row m = l15 (+a*16), k-chunks l4*8 and 32+l4*8.
    // Both hi and lo of x are kept (x is exact: xh + xl).
    short8 ahA[2], alA[2], ahB[2], alB[2];
#pragma unroll
    for (int a = 0; a < 2; a++) {
        const float* base = enc + (size_t)(vb + a * 16 + l15) * DQ + l4 * 8;
        const float4* p0 = (const float4*)base;
        const float4* p1 = (const float4*)(base + 32);
        cvt8(p0[0], p0[1], ahA[a], alA[a]);
        cvt8(p1[0], p1[1], ahB[a], alB[a]);
    }

    // Packed cascade state: m1/m2 are d2' with the 9-bit code in the low
    // mantissa bits (perturbation <=0.016, inside the rescan threshold).
    float m1[8], m2[8];
#pragma unroll
    for (int r = 0; r < 8; r++) { m1[r] = 3.4e38f; m2[r] = 3.4e38f; }

    // Swizzled B-frag slot offsets (elements); key = l15&7.
    const int sl0 = (l4 ^ (l15 & 7)) * 8;    // chunk l4     (dims l4*8..+8)
    const int sl1 = sl0 ^ 32;                // chunk 4+l4   (dims 32+l4*8..+8)

    // Staging: thread stages 32 B of hi per stage (two b128 writes).
    short8 rh0 = *(const short8*)(ehi + tid * 8);
    short8 rh1 = *(const short8*)(ehi + 2048 + tid * 8);
    // write stage 0 into buf 0
    *(short8*)(hs + tid * 8) = rh0;  *(short8*)(hs + 2048 + tid * 8) = rh1;
    // prefetch stage 1 into regs
    rh0 = *(const short8*)(ehi + SDQ + tid * 8);
    rh1 = *(const short8*)(ehi + SDQ + 2048 + tid * 8);

#define LDB(H0, H1, S) { const int _o = ((S) * 16 + l15) * DQ; \
    H0 = *(const short8*)(hb + _o + sl0); H1 = *(const short8*)(hb + _o + sl1); }

#define BODY(ST, S, BH0, BH1) { \
    const int code = (ST) * SC + (S) * 16 + l15; \
    const float ev = esq_s[code]; \
    _Pragma("unroll") \
    for (int a = 0; a < 2; a++) { \
        f32x4 acc = {0.f, 0.f, 0.f, 0.f}; \
        acc = __builtin_amdgcn_mfma_f32_16x16x32_bf16(ahA[a], BH0, acc, 0, 0, 0); \
        acc = __builtin_amdgcn_mfma_f32_16x16x32_bf16(ahB[a], BH1, acc, 0, 0, 0); \
        acc = __builtin_amdgcn_mfma_f32_16x16x32_bf16(alA[a], BH0, acc, 0, 0, 0); \
        acc = __builtin_amdgcn_mfma_f32_16x16x32_bf16(alB[a], BH1, acc, 0, 0, 0); \
        _Pragma("unroll") \
        for (int r = 0; r < 4; r++) { \
            float v = fmaf(-2.0f, acc[r], ev); \
            float p = __uint_as_float((__float_as_uint(v) & 0xFFFFFE00u) | (unsigned)code); \
            m2[a * 4 + r] = fminf(m2[a * 4 + r], fmaxf(m1[a * 4 + r], p)); \
            m1[a * 4 + r] = fminf(m1[a * 4 + r], p); \
        } \
    } }

    for (int st = 0; st < NST; st++) {
        // Drains: LDS writes of buf[st&1] (last iter) + global loads issued
        // last iter (they had a full stage of compute cover).
        __syncthreads();
        if (st < NST - 1) {                  // write stage st+1 into other buf
            unsigned short* hw = hs + ((st + 1) & 1) * SDQ_P;
            *(short8*)(hw + tid * 8) = rh0;  *(short8*)(hw + 2048 + tid * 8) = rh1;
        }
        if (st < NST - 2) {                  // prefetch stage st+2 (overlaps compute)
            const int o = (st + 2) * SDQ;
            rh0 = *(const short8*)(ehi + o + tid * 8);
            rh1 = *(const short8*)(ehi + o + 2048 + tid * 8);
        }
        const unsigned short* hb = hs + (st & 1) * SDQ_P;
        // 4 sub-tiles, even/odd B double-buffer in regs (pure LDS->MFMA->VALU)
        short8 b0h0, b0h1, b1h0, b1h1;
        LDB(b0h0, b0h1, 0)
        LDB(b1h0, b1h1, 1)
        BODY(st, 0, b0h0, b0h1)
        LDB(b0h0, b0h1, 2)
        BODY(st, 1, b1h0, b1h1)
        LDB(b1h0, b1h1, 3)
        BODY(st, 2, b0h0, b0h1)
        BODY(st, 3, b1h0, b1h1)
    }
#undef LDB
#undef BODY

    // Cross-lane merge over the 16 cols (xor on lane&15 bits); packed values
    // carry their code along.
#pragma unroll
    for (int m = 1; m <= 8; m <<= 1) {
#pragma unroll
        for (int r = 0; r < 8; r++) {
            float o1 = __shfl_xor(m1[r], m);
            float o2 = __shfl_xor(m2[r], m);
            m2[r] = fminf(fminf(m2[r], o2), fmaxf(m1[r], o1));
            m1[r] = fminf(m1[r], o1);
        }
    }

    if (l15 == 0) {
#pragma unroll
        for (int a = 0; a < 2; a++)
#pragma unroll
            for (int r = 0; r < 4; r++) {
                const int row = a * 16 + l4 * 4 + r;
                bidx_s[w * RPW + row] = (int)(__float_as_uint(m1[a * 4 + r]) & 511u);
                flag_s[w * RPW + row] = (m2[a * 4 + r] - m1[a * 4 + r] < TIE_THR) ? 1 : 0;
            }
    }
    // bidx_s/flag_s are per-wave segments -> wave-internal visibility only.

    // Exact fp64 rescan of flagged rows (wave-uniform branch, wave-parallel:
    // 8 codes/lane, packed u64 min). Rate ~5-10% of rows at thr 0.2.
    for (int row = 0; row < RPW; row++) {
        if (flag_s[w * RPW + row]) {
            const int v = vb + row;
            const float4* xe = (const float4*)(enc + (size_t)v * DQ);
            unsigned long long best = ~0ULL;
            for (int q = 0; q < 8; q++) {
                const int c = lane * 8 + q;
                const float4* ee = (const float4*)(embed + (size_t)c * DQ);
                double a = 0.0;
                for (int j = 0; j < 16; j++) {          // global ptrs: runtime j fine
                    float4 xx = xe[j], ez = ee[j];
                    double d0 = (double)xx.x - (double)ez.x; a = fma(d0, d0, a);
                    double d1 = (double)xx.y - (double)ez.y; a = fma(d1, d1, a);
                    double d2 = (double)xx.z - (double)ez.z; a = fma(d2, d2, a);
                    double d3 = (double)xx.w - (double)ez.w; a = fma(d3, d3, a);
                }
                unsigned long long p =
                    (((unsigned long long)__double_as_longlong(a)) & ~511ULL) | (unsigned)c;
                best = (p < best) ? p : best;
            }
#pragma unroll
            for (int mm = 1; mm < 64; mm <<= 1) {
                unsigned long long ob = (unsigned long long)__shfl_xor((long long)best, mm);
                best = (ob < best) ? ob : best;
            }
            if (lane == 0) bidx_s[w * RPW + row] = (int)(best & 511ULL);
        }
    }

    // Epilogue: per tile a, lane handles row a*16+l15, chunks l4*8 and 32+l4*8.
    // x recomputed from the hi/lo frags (exact split; ~1e-5 rel err loss-only).
    float lsum = 0.f;
#pragma unroll
    for (int a = 0; a < 2; a++) {
        const int myv = vb + a * 16 + l15;
        const int qb = bidx_s[w * RPW + a * 16 + l15];
        const float* qbase = embed + (size_t)qb * DQ + l4 * 8;
        const float4* qa = (const float4*)qbase;
        const float4* qc = (const float4*)(qbase + 32);
        float4 q0 = qa[0], q1 = qa[1], q2 = qc[0], q3 = qc[1];
        float* obase = out + (size_t)myv * DQ + l4 * 8;
        ((float4*)obase)[0] = q0; ((float4*)obase)[1] = q1;
        ((float4*)(obase + 32))[0] = q2; ((float4*)(obase + 32))[1] = q3;
        if (l4 == 0) out[IDX_OFF + myv] = (float)qb;

        float d;
        d = q0.x - (bf2f(ahA[a][0]) + bf2f(alA[a][0])); lsum = fmaf(d, d, lsum);
        d = q0.y - (bf2f(ahA[a][1]) + bf2f(alA[a][1])); lsum = fmaf(d, d, lsum);
        d = q0.z - (bf2f(ahA[a][2]) + bf2f(alA[a][2])); lsum = fmaf(d, d, lsum);
        d = q0.w - (bf2f(ahA[a][3]) + bf2f(alA[a][3])); lsum = fmaf(d, d, lsum);
        d = q1.x - (bf2f(ahA[a][4]) + bf2f(alA[a][4])); lsum = fmaf(d, d, lsum);
        d = q1.y - (bf2f(ahA[a][5]) + bf2f(alA[a][5])); lsum = fmaf(d, d, lsum);
        d = q1.z - (bf2f(ahA[a][6]) + bf2f(alA[a][6])); lsum = fmaf(d, d, lsum);
        d = q1.w - (bf2f(ahA[a][7]) + bf2f(alA[a][7])); lsum = fmaf(d, d, lsum);
        d = q2.x - (bf2f(ahB[a][0]) + bf2f(alB[a][0])); lsum = fmaf(d, d, lsum);
        d = q2.y - (bf2f(ahB[a][1]) + bf2f(alB[a][1])); lsum = fmaf(d, d, lsum);
        d = q2.z - (bf2f(ahB[a][2]) + bf2f(alB[a][2])); lsum = fmaf(d, d, lsum);
        d = q2.w - (bf2f(ahB[a][3]) + bf2f(alB[a][3])); lsum = fmaf(d, d, lsum);
        d = q3.x - (bf2f(ahB[a][4]) + bf2f(alB[a][4])); lsum = fmaf(d, d, lsum);
        d = q3.y - (bf2f(ahB[a][5]) + bf2f(alB[a][5])); lsum = fmaf(d, d, lsum);
        d = q3.z - (bf2f(ahB[a][6]) + bf2f(alB[a][6])); lsum = fmaf(d, d, lsum);
        d = q3.w - (bf2f(ahB[a][7]) + bf2f(alB[a][7])); lsum = fmaf(d, d, lsum);
    }

#pragma unroll
    for (int off = 32; off > 0; off >>= 1) lsum += __shfl_down(lsum, off);
    if (lane == 0) red[w] = lsum;
    __syncthreads();
    if (tid == 0) {
        float s = (red[0] + red[1]) + (red[2] + red[3]);
        atomicAdd(out + LOSS_OFF, s * (2.0f / (float)QOUT_SIZE));
    }
}

extern "C" void kernel_launch(void* const* d_in, const int* in_sizes, int n_in,
                              void* d_out, int out_size, void* d_ws, size_t ws_size,
                              hipStream_t stream) {
    const float* enc = (const float*)d_in[0];
    const float* embed = (const float*)d_in[1];
    float* out = (float*)d_out;
    // ws layout: ehi[512*64] u16 | esq[512] f32  (~66 KB)
    unsigned short* ehi = (unsigned short*)d_ws;
    float* esq = (float*)(ehi + KQ * DQ);

    hipLaunchKernelGGL(vq_init_kernel, dim3(64), dim3(64), 0, stream,
                       embed, ehi, esq, out);
    hipLaunchKernelGGL(vq_mfma_kernel, dim3(NBLK), dim3(256), 0, stream,
                       enc, embed, ehi, esq, out);
}

// Round 15
// 168.813 us; speedup vs baseline: 1.6500x; 1.6500x over previous
//
#include <hip/hip_runtime.h>
#include <math.h>

// Problem constants (fixed by reference: enc (32,64,64,64) fp32, embed (512,64) fp32)
#define DQ 64
#define KQ 512
#define NVEC 131072
#define QOUT_SIZE (NVEC * DQ)              // 8388608
#define LOSS_OFF QOUT_SIZE
#define IDX_OFF (QOUT_SIZE + 1)

#define RPW 32                             // rows per wave (2 MFMA A-tiles)
#define WPB 4                              // waves per block (256 threads)
#define VPB (RPW * WPB)                    // 128 rows per block
#define NBLK (NVEC / VPB)                  // 1024 blocks -> 4 per CU
#define SC 64                              // codes per LDS stage
#define NST (KQ / SC)                      // 8 stages
#define SDQ (SC * DQ)                      // 4096 shorts per stage buffer
#define TIE_THR 0.05f                      // rescan when packed top-2 gap below this
// Error budget: 6-MFMA surrogate (exact-split x, hi+lo e) err ~3e-4; mantissa
// packing perturbs each value by <=512 ulp(|v|~256) ~ 0.016 (0.032 on a gap).
// Unflagged => packed gap >= 0.05 => surrogate gap >= 0.018 => true argmin kept.

typedef __attribute__((ext_vector_type(8))) short short8;          // 8 bf16 = 1 MFMA A/B frag
typedef __attribute__((ext_vector_type(4))) float f32x4;           // MFMA C/D frag

static __device__ __forceinline__ unsigned short f2bf(float f) {   // RNE fp32->bf16
    unsigned u = __float_as_uint(f);
    u += 0x7fff + ((u >> 16) & 1);
    return (unsigned short)(u >> 16);
}
static __device__ __forceinline__ float bf2f(unsigned short h) {
    return __uint_as_float(((unsigned)h) << 16);
}
static __device__ __forceinline__ void cvt8(float4 a, float4 b, short8& hi, short8& lo) {
#define C1(I, V) { unsigned short _h = f2bf(V); hi[I] = (short)_h; lo[I] = (short)f2bf((V) - bf2f(_h)); }
    C1(0, a.x) C1(1, a.y) C1(2, a.z) C1(3, a.w)
    C1(4, b.x) C1(5, b.y) C1(6, b.z) C1(7, b.w)
#undef C1
}

// Init: hi/lo bf16 codebook in XOR-SWIZZLED layout (chunk c of row k stored at
// slot c ^ (k&7)) so main-kernel ds_read_b128 B-frag reads are 2-way max
// (free), while staging stays a verbatim contiguous copy. Plus e_sq + loss=0.
__global__ void vq_init_kernel(const float* __restrict__ embed,
                               unsigned short* __restrict__ ehi,
                               unsigned short* __restrict__ elo,
                               float* __restrict__ esq,
                               float* __restrict__ out) {
    const int t = blockIdx.x * 64 + threadIdx.x;   // 0..4095
    if (t == 0) out[LOSS_OFF] = 0.0f;
    const int k = t >> 3;            // codebook row
    const int c = t & 7;             // 16-byte chunk (8 dims)
    const float4* p = (const float4*)(embed + (size_t)k * DQ + c * 8);
    float4 a = p[0], b = p[1];
    short8 hi, lo;
    cvt8(a, b, hi, lo);
    const int slot = c ^ (k & 7);    // XOR swizzle
    *(short8*)(ehi + (size_t)k * DQ + slot * 8) = hi;
    *(short8*)(elo + (size_t)k * DQ + slot * 8) = lo;

    float ps = 0.f;
    ps = fmaf(a.x, a.x, ps); ps = fmaf(a.y, a.y, ps); ps = fmaf(a.z, a.z, ps); ps = fmaf(a.w, a.w, ps);
    ps = fmaf(b.x, b.x, ps); ps = fmaf(b.y, b.y, ps); ps = fmaf(b.z, b.z, ps); ps = fmaf(b.w, b.w, ps);
    ps += __shfl_xor(ps, 1);
    ps += __shfl_xor(ps, 2);
    ps += __shfl_xor(ps, 4);
    if (c == 0) esq[k] = ps;
}

// REVERT to R13 base (74.6 us proven; R14's cheap surrogate blew up the fp64
// rescan rate and doubled absolute VALU time -> 214 us). Two surgical changes:
// (1) the 6 MFMAs per acc are split into TWO independent 3-chains summed at
//     the end -> MFMA dependency path halves (R13 was latency-bound with all
//     pipes <30%); (2) the 9-bit code rides in the d2 mantissa (kills i1[8],
//     -8 regs, fewer cascade ops) with TIE_THR=0.05 covering pack+surrogate
//     error (rescan rate ~1%, the regime R13 already proved cheap).
// R12/R13 allocator rule: budget = 512/(provable waves/SIMD); LDS ~35.5 KB
// -> 4 WGs/CU -> 128 regs; demand ~116 fits, no spill.
// R6-R9: no global loads in the k-loop. R3: unrolled-constant reg indexing.
__global__ __launch_bounds__(256) void vq_mfma_kernel(const float* __restrict__ enc,
                                                      const float* __restrict__ embed,
                                                      const unsigned short* __restrict__ ehi,
                                                      const unsigned short* __restrict__ elo,
                                                      const float* __restrict__ esq,
                                                      float* __restrict__ out) {
    __shared__ unsigned short hs[2 * SDQ];     // hi stages (dbuf): 16 KB
    __shared__ unsigned short ls_[2 * SDQ];    // lo stages (dbuf): 16 KB
    __shared__ float esq_s[KQ];                // 2 KB
    __shared__ int bidx_s[VPB];                // 0.5 KB
    __shared__ int flag_s[VPB];                // 0.5 KB
    __shared__ float red[WPB];

    const int tid = threadIdx.x;
    const int lane = tid & 63;
    const int w = tid >> 6;            // wave 0..3
    const int l15 = lane & 15;
    const int l4 = lane >> 4;          // 0..3
    const int vb = blockIdx.x * VPB + w * RPW;

    esq_s[tid] = esq[tid];
    esq_s[tid + 256] = esq[tid + 256];

    // A fragments for 2 tiles: row m = l15 (+a*16), k-chunks l4*8 and 32+l4*8.
    short8 ahA[2], alA[2], ahB[2], alB[2];
#pragma unroll
    for (int a = 0; a < 2; a++) {
        const float* base = enc + (size_t)(vb + a * 16 + l15) * DQ + l4 * 8;
        const float4* p0 = (const float4*)base;
        const float4* p1 = (const float4*)(base + 32);
        cvt8(p0[0], p0[1], ahA[a], alA[a]);
        cvt8(p1[0], p1[1], ahB[a], alB[a]);
    }

    // Packed cascade state: m1/m2 carry the 9-bit code in the low mantissa.
    float m1[8], m2[8];
#pragma unroll
    for (int r = 0; r < 8; r++) { m1[r] = 3.4e38f; m2[r] = 3.4e38f; }

    // Swizzled B-frag slot offsets (elements); key = l15&7.
    const int sl0 = (l4 ^ (l15 & 7)) * 8;    // chunk l4     (dims l4*8..+8)
    const int sl1 = sl0 ^ 32;                // chunk 4+l4   (dims 32+l4*8..+8)

    // Staging: thread stages 32 B hi + 32 B lo per stage (two b128 writes each).
    short8 rh0 = *(const short8*)(ehi + tid * 8);
    short8 rh1 = *(const short8*)(ehi + 2048 + tid * 8);
    short8 rl0 = *(const short8*)(elo + tid * 8);
    short8 rl1 = *(const short8*)(elo + 2048 + tid * 8);
    // write stage 0 into buf 0
    *(short8*)(hs + tid * 8) = rh0;  *(short8*)(hs + 2048 + tid * 8) = rh1;
    *(short8*)(ls_ + tid * 8) = rl0; *(short8*)(ls_ + 2048 + tid * 8) = rl1;
    // prefetch stage 1 into regs
    rh0 = *(const short8*)(ehi + SDQ + tid * 8);
    rh1 = *(const short8*)(ehi + SDQ + 2048 + tid * 8);
    rl0 = *(const short8*)(elo + SDQ + tid * 8);
    rl1 = *(const short8*)(elo + SDQ + 2048 + tid * 8);

#define LDB(H0, H1, L0, L1, S) { const int _o = ((S) * 16 + l15) * DQ; \
    H0 = *(const short8*)(hb + _o + sl0); H1 = *(const short8*)(hb + _o + sl1); \
    L0 = *(const short8*)(lb + _o + sl0); L1 = *(const short8*)(lb + _o + sl1); }

// Two independent 3-MFMA chains per acc (halved dependency path), summed once.
#define BODY(ST, S, BH0, BH1, BL0, BL1) { \
    const int code = (ST) * SC + (S) * 16 + l15; \
    const float ev = esq_s[code]; \
    _Pragma("unroll") \
    for (int a = 0; a < 2; a++) { \
        f32x4 acp = {0.f, 0.f, 0.f, 0.f}; \
        f32x4 acq = {0.f, 0.f, 0.f, 0.f}; \
        acp = __builtin_amdgcn_mfma_f32_16x16x32_bf16(ahA[a], BH0, acp, 0, 0, 0); \
        acq = __builtin_amdgcn_mfma_f32_16x16x32_bf16(ahB[a], BH1, acq, 0, 0, 0); \
        acp = __builtin_amdgcn_mfma_f32_16x16x32_bf16(alA[a], BH0, acp, 0, 0, 0); \
        acq = __builtin_amdgcn_mfma_f32_16x16x32_bf16(alB[a], BH1, acq, 0, 0, 0); \
        acp = __builtin_amdgcn_mfma_f32_16x16x32_bf16(ahA[a], BL0, acp, 0, 0, 0); \
        acq = __builtin_amdgcn_mfma_f32_16x16x32_bf16(ahB[a], BL1, acq, 0, 0, 0); \
        _Pragma("unroll") \
        for (int r = 0; r < 4; r++) { \
            float v = fmaf(-2.0f, acp[r] + acq[r], ev); \
            float p = __uint_as_float((__float_as_uint(v) & 0xFFFFFE00u) | (unsigned)code); \
            m2[a * 4 + r] = fminf(m2[a * 4 + r], fmaxf(m1[a * 4 + r], p)); \
            m1[a * 4 + r] = fminf(m1[a * 4 + r], p); \
        } \
    } }

    for (int st = 0; st < NST; st++) {
        // Drains: LDS writes of buf[st&1] (last iter) + global loads issued
        // last iter (they had a full stage of compute cover).
        __syncthreads();
        if (st < NST - 1) {                  // write stage st+1 into other buf
            unsigned short* hw = hs + ((st + 1) & 1) * SDQ;
            unsigned short* lw = ls_ + ((st + 1) & 1) * SDQ;
            *(short8*)(hw + tid * 8) = rh0;  *(short8*)(hw + 2048 + tid * 8) = rh1;
            *(short8*)(lw + tid * 8) = rl0;  *(short8*)(lw + 2048 + tid * 8) = rl1;
        }
        if (st < NST - 2) {                  // prefetch stage st+2 (overlaps compute)
            const int o = (st + 2) * SDQ;
            rh0 = *(const short8*)(ehi + o + tid * 8);
            rh1 = *(const short8*)(ehi + o + 2048 + tid * 8);
            rl0 = *(const short8*)(elo + o + tid * 8);
            rl1 = *(const short8*)(elo + o + 2048 + tid * 8);
        }
        const unsigned short* hb = hs + (st & 1) * SDQ;
        const unsigned short* lb = ls_ + (st & 1) * SDQ;
        // 4 sub-tiles, even/odd B double-buffer in regs (pure LDS->MFMA->VALU)
        short8 b0h0, b0h1, b0l0, b0l1, b1h0, b1h1, b1l0, b1l1;
        LDB(b0h0, b0h1, b0l0, b0l1, 0)
        LDB(b1h0, b1h1, b1l0, b1l1, 1)
        BODY(st, 0, b0h0, b0h1, b0l0, b0l1)
        LDB(b0h0, b0h1, b0l0, b0l1, 2)
        BODY(st, 1, b1h0, b1h1, b1l0, b1l1)
        LDB(b1h0, b1h1, b1l0, b1l1, 3)
        BODY(st, 2, b0h0, b0h1, b0l0, b0l1)
        BODY(st, 3, b1h0, b1h1, b1l0, b1l1)
    }
#undef LDB
#undef BODY

    // Cross-lane merge over the 16 cols (xor on lane&15 bits); packed values
    // carry their code along.
#pragma unroll
    for (int m = 1; m <= 8; m <<= 1) {
#pragma unroll
        for (int r = 0; r < 8; r++) {
            float o1 = __shfl_xor(m1[r], m);
            float o2 = __shfl_xor(m2[r], m);
            m2[r] = fminf(fminf(m2[r], o2), fmaxf(m1[r], o1));
            m1[r] = fminf(m1[r], o1);
        }
    }

    if (l15 == 0) {
#pragma unroll
        for (int a = 0; a < 2; a++)
#pragma unroll
            for (int r = 0; r < 4; r++) {
                const int row = a * 16 + l4 * 4 + r;
                bidx_s[w * RPW + row] = (int)(__float_as_uint(m1[a * 4 + r]) & 511u);
                flag_s[w * RPW + row] = (m2[a * 4 + r] - m1[a * 4 + r] < TIE_THR) ? 1 : 0;
            }
    }
    // bidx_s/flag_s are per-wave segments -> wave-internal visibility only.

    // Exact fp64 rescan of flagged rows (wave-uniform branch, wave-parallel:
    // 8 codes/lane, packed u64 min). Rate ~1% at thr 0.05 w/ accurate surrogate.
    for (int row = 0; row < RPW; row++) {
        if (flag_s[w * RPW + row]) {
            const int v = vb + row;
            const float4* xe = (const float4*)(enc + (size_t)v * DQ);
            unsigned long long best = ~0ULL;
            for (int q = 0; q < 8; q++) {
                const int c = lane * 8 + q;
                const float4* ee = (const float4*)(embed + (size_t)c * DQ);
                double a = 0.0;
                for (int j = 0; j < 16; j++) {          // global ptrs: runtime j fine
                    float4 xx = xe[j], ez = ee[j];
                    double d0 = (double)xx.x - (double)ez.x; a = fma(d0, d0, a);
                    double d1 = (double)xx.y - (double)ez.y; a = fma(d1, d1, a);
                    double d2 = (double)xx.z - (double)ez.z; a = fma(d2, d2, a);
                    double d3 = (double)xx.w - (double)ez.w; a = fma(d3, d3, a);
                }
                unsigned long long p =
                    (((unsigned long long)__double_as_longlong(a)) & ~511ULL) | (unsigned)c;
                best = (p < best) ? p : best;
            }
#pragma unroll
            for (int mm = 1; mm < 64; mm <<= 1) {
                unsigned long long ob = (unsigned long long)__shfl_xor((long long)best, mm);
                best = (ob < best) ? ob : best;
            }
            if (lane == 0) bidx_s[w * RPW + row] = (int)(best & 511ULL);
        }
    }

    // Epilogue: per tile a, lane handles row a*16+l15, chunks l4*8 and 32+l4*8.
    // x recomputed from the hi/lo frags (exact split; ~1e-5 rel err loss-only).
    float lsum = 0.f;
#pragma unroll
    for (int a = 0; a < 2; a++) {
        const int myv = vb + a * 16 + l15;
        const int qb = bidx_s[w * RPW + a * 16 + l15];
        const float* qbase = embed + (size_t)qb * DQ + l4 * 8;
        const float4* qa = (const float4*)qbase;
        const float4* qc = (const float4*)(qbase + 32);
        float4 q0 = qa[0], q1 = qa[1], q2 = qc[0], q3 = qc[1];
        float* obase = out + (size_t)myv * DQ + l4 * 8;
        ((float4*)obase)[0] = q0; ((float4*)obase)[1] = q1;
        ((float4*)(obase + 32))[0] = q2; ((float4*)(obase + 32))[1] = q3;
        if (l4 == 0) out[IDX_OFF + myv] = (float)qb;

        float d;
        d = q0.x - (bf2f(ahA[a][0]) + bf2f(alA[a][0])); lsum = fmaf(d, d, lsum);
        d = q0.y - (bf2f(ahA[a][1]) + bf2f(alA[a][1])); lsum = fmaf(d, d, lsum);
        d = q0.z - (bf2f(ahA[a][2]) + bf2f(alA[a][2])); lsum = fmaf(d, d, lsum);
        d = q0.w - (bf2f(ahA[a][3]) + bf2f(alA[a][3])); lsum = fmaf(d, d, lsum);
        d = q1.x - (bf2f(ahA[a][4]) + bf2f(alA[a][4])); lsum = fmaf(d, d, lsum);
        d = q1.y - (bf2f(ahA[a][5]) + bf2f(alA[a][5])); lsum = fmaf(d, d, lsum);
        d = q1.z - (bf2f(ahA[a][6]) + bf2f(alA[a][6])); lsum = fmaf(d, d, lsum);
        d = q1.w - (bf2f(ahA[a][7]) + bf2f(alA[a][7])); lsum = fmaf(d, d, lsum);
        d = q2.x - (bf2f(ahB[a][0]) + bf2f(alB[a][0])); lsum = fmaf(d, d, lsum);
        d = q2.y - (bf2f(ahB[a][1]) + bf2f(alB[a][1])); lsum = fmaf(d, d, lsum);
        d = q2.z - (bf2f(ahB[a][2]) + bf2f(alB[a][2])); lsum = fmaf(d, d, lsum);
        d = q2.w - (bf2f(ahB[a][3]) + bf2f(alB[a][3])); lsum = fmaf(d, d, lsum);
        d = q3.x - (bf2f(ahB[a][4]) + bf2f(alB[a][4])); lsum = fmaf(d, d, lsum);
        d = q3.y - (bf2f(ahB[a][5]) + bf2f(alB[a][5])); lsum = fmaf(d, d, lsum);
        d = q3.z - (bf2f(ahB[a][6]) + bf2f(alB[a][6])); lsum = fmaf(d, d, lsum);
        d = q3.w - (bf2f(ahB[a][7]) + bf2f(alB[a][7])); lsum = fmaf(d, d, lsum);
    }

#pragma unroll
    for (int off = 32; off > 0; off >>= 1) lsum += __shfl_down(lsum, off);
    if (lane == 0) red[w] = lsum;
    __syncthreads();
    if (tid == 0) {
        float s = (red[0] + red[1]) + (red[2] + red[3]);
        atomicAdd(out + LOSS_OFF, s * (2.0f / (float)QOUT_SIZE));
    }
}

extern "C" void kernel_launch(void* const* d_in, const int* in_sizes, int n_in,
                              void* d_out, int out_size, void* d_ws, size_t ws_size,
                              hipStream_t stream) {
    const float* enc = (const float*)d_in[0];
    const float* embed = (const float*)d_in[1];
    float* out = (float*)d_out;
    // ws layout: ehi[512*64] u16 | elo[512*64] u16 | esq[512] f32  (~130 KB)
    unsigned short* ehi = (unsigned short*)d_ws;
    unsigned short* elo = ehi + KQ * DQ;
    float* esq = (float*)(elo + KQ * DQ);

    hipLaunchKernelGGL(vq_init_kernel, dim3(64), dim3(64), 0, stream,
                       embed, ehi, elo, esq, out);
    hipLaunchKernelGGL(vq_mfma_kernel, dim3(NBLK), dim3(256), 0, stream,
                       enc, embed, ehi, elo, esq, out);
}